// Round 5
// baseline (829.730 us; speedup 1.0000x reference)
//
#include <hip/hip_runtime.h>
#include <hip/hip_fp16.h>
#include <stdint.h>

// GCN forward. N=100000, E=3000000, G=256, F_IN=64, NHID=32.
// R1: 96M scatter-atomics = L2 atomic ceiling. -> gather.
// R2: naive CSR build: 16x write amplification across 8 incoherent L2s.
// R3: XCD-sliced build; gather latency-bound.
// R4: fp16 halved gather lines; dur unchanged -> MLP/latency bound, and
//     ~450us hidden in build kernels (cursor atomics, 8x re-reads, scans).
// R5: 64-node buckets. Offsets fully precomputed (zero global atomics in
//     scatter), 8-slice XCD-local writes, edge-parallel gather into LDS
//     tiles (independent edges -> deep MLP), degree + pool fused per bucket.

#define BLK 256
#define NCHUNK 512          // edge chunks for count/scatter
#define MAXNB 1600          // max buckets (N<=102400)

// K1: edge class from masks (masks exactly cover E).
__global__ void k1_cls(const int* __restrict__ km, const int* __restrict__ um,
                       const int* __restrict__ om, int s0, int s1, int s2,
                       uint8_t* __restrict__ ewc) {
    int i = blockIdx.x * blockDim.x + threadIdx.x;
    int total = s0 + s1 + s2;
    if (i >= total) return;
    int e, cls;
    if (i < s0)           { e = km[i];           cls = 0; }
    else if (i < s0 + s1) { e = um[i - s0];      cls = 1; }
    else                  { e = om[i - s0 - s1]; cls = 2; }
    ewc[e] = (uint8_t)cls;
}

// kA: per-chunk bucket histogram (LDS), coalesced row write cnt[c][b].
__global__ void kA_count(const int* __restrict__ col, int* __restrict__ cnt,
                         int n_edges, int NB) {
    __shared__ int lh[MAXNB];
    int t = threadIdx.x, c = blockIdx.x;
    for (int b = t; b < NB; b += BLK) lh[b] = 0;
    __syncthreads();
    int chunk = (n_edges + NCHUNK - 1) / NCHUNK;
    int e0 = c * chunk, e1 = min(e0 + chunk, n_edges);
    for (int e = e0 + t; e < e1; e += BLK) atomicAdd(&lh[col[e] >> 6], 1);
    __syncthreads();
    for (int b = t; b < NB; b += BLK) cnt[(size_t)c * NB + b] = lh[b];
}

// kB_col: per bucket b, exclusive scan over chunks of cnt[c][b]
// -> offT[b][c] (coalesced write), and tot[b].
__global__ void kB_col(const int* __restrict__ cnt, int* __restrict__ offT,
                       int* __restrict__ tot, int NB) {
    __shared__ int s[BLK];
    int b = blockIdx.x, t = threadIdx.x;
    int a0 = cnt[(size_t)(2 * t) * NB + b];
    int a1 = cnt[(size_t)(2 * t + 1) * NB + b];
    s[t] = a0 + a1; __syncthreads();
    for (int st = 1; st < BLK; st <<= 1) {
        int v = (t >= st) ? s[t - st] : 0;
        __syncthreads(); s[t] += v; __syncthreads();
    }
    int ex = (t == 0) ? 0 : s[t - 1];
    offT[(size_t)b * NCHUNK + 2 * t]     = ex;
    offT[(size_t)b * NCHUNK + 2 * t + 1] = ex + a0;
    if (t == BLK - 1) tot[b] = s[BLK - 1];
}

// kBase: single-block exclusive scan of tot[NB] -> base_[0..NB] (base_[NB]=E).
__global__ void kBase(const int* __restrict__ tot, int* __restrict__ base_, int NB) {
    __shared__ int s[BLK];
    const int K = 7;  // 256*7 = 1792 >= MAXNB
    int t = threadIdx.x;
    int v[K]; int sum = 0;
#pragma unroll
    for (int k = 0; k < K; ++k) {
        int i = t * K + k;
        v[k] = (i < NB) ? tot[i] : 0;
        sum += v[k];
    }
    s[t] = sum; __syncthreads();
    for (int st = 1; st < BLK; st <<= 1) {
        int x = (t >= st) ? s[t - st] : 0;
        __syncthreads(); s[t] += x; __syncthreads();
    }
    int ex = (t == 0) ? 0 : s[t - 1];
#pragma unroll
    for (int k = 0; k < K; ++k) {
        int i = t * K + k;
        if (i < NB) base_[i] = ex;
        ex += v[k];
    }
    if (t == BLK - 1) base_[NB] = s[BLK - 1];
}

// kC: 8-slice XCD-partitioned scatter into bucket lists. Zero global atomics:
// each (chunk c, bucket b) range is exclusive, cursor = base_[b]+offT[b][c]
// kept in LDS. Entry = (local_col<<19)|(row<<2)|cls.
__global__ void kC_scatter(const int* __restrict__ row, const int* __restrict__ col,
                           const uint8_t* __restrict__ ewc, const int* __restrict__ base_,
                           const int* __restrict__ offT, int* __restrict__ csrB,
                           int n_edges, int NB, int nbs) {
    __shared__ int cur[256];
    int sl = blockIdx.x & 7, c = blockIdx.x >> 3, t = threadIdx.x;
    int b0 = sl * nbs, b1 = min(b0 + nbs, NB);
    for (int b = b0 + t; b < b1; b += BLK)
        cur[b - b0] = base_[b] + offT[(size_t)b * NCHUNK + c];
    __syncthreads();
    int chunk = (n_edges + NCHUNK - 1) / NCHUNK;
    int e0 = c * chunk, e1 = min(e0 + chunk, n_edges);
    for (int e = e0 + t; e < e1; e += BLK) {
        int cc = col[e]; int b = cc >> 6;
        if (b >= b0 && b < b1) {
            int pos = atomicAdd(&cur[b - b0], 1);
            csrB[pos] = ((cc & 63) << 19) | (row[e] << 2) | ewc[e];
        }
    }
}

// kDeg: per-bucket weighted degree from bucket list -> dinv = rsqrt(deg+1).
__global__ void kDeg(const int* __restrict__ base_, const int* __restrict__ csrB,
                     const float* __restrict__ mw, float* __restrict__ dinv, int n_nodes) {
    __shared__ float ldeg[64];
    int b = blockIdx.x, t = threadIdx.x;
    if (t < 64) ldeg[t] = 0.0f;
    __syncthreads();
    float a = mw[0], bb = mw[1], c3 = mw[2];
    float m = fmaxf(a, fmaxf(bb, c3));
    float ea = __expf(a - m), eb = __expf(bb - m), ec = __expf(c3 - m);
    float inv = 1.0f / (ea + eb + ec);
    float w0 = ea * inv, w1 = eb * inv, w2 = ec * inv;
    int p0 = base_[b], p1 = base_[b + 1];
    for (int p = p0 + t; p < p1; p += BLK) {
        int e = csrB[p]; int lc = e >> 19; int cls = e & 3;
        float w = (cls == 0) ? w0 : ((cls == 1) ? w1 : w2);
        atomicAdd(&ldeg[lc], w);
    }
    __syncthreads();
    if (t < 64) {
        int n = b * 64 + t;
        if (n < n_nodes) dinv[n] = rsqrtf(ldeg[t] + 1.0f);
    }
}

// k3: fold emb through gcn: Wfull[0,j]=gcn_W[0,j]; Wfull[1+m,j]=emb_W[m,:]@gcn_W[1:,j]
__global__ void k3_weights(const float* __restrict__ emb_W, const float* __restrict__ emb_b,
                           const float* __restrict__ gcn_W,
                           float* __restrict__ Wfull, float* __restrict__ hWbias) {
    int t = threadIdx.x;
    for (int idx = t; idx < 64 * 32; idx += blockDim.x) {
        int k = idx >> 5, j = idx & 31;
        float acc;
        if (k == 0) {
            acc = gcn_W[j];
        } else {
            int m = k - 1;
            acc = 0.0f;
            for (int tt = 0; tt < 63; ++tt)
                acc += emb_W[m * 63 + tt] * gcn_W[(1 + tt) * 32 + j];
        }
        Wfull[idx] = acc;
    }
    if (t < 32) {
        float acc = 0.0f;
        for (int tt = 0; tt < 63; ++tt)
            acc += emb_b[tt] * gcn_W[(1 + tt) * 32 + t];
        hWbias[t] = acc;
    }
}

// k4: hWs[n,:] = fp16( dinv[n] * (x[n,:] @ Wfull + hWbias) )
__global__ void k4_gemm(const float* __restrict__ x, const float* __restrict__ Wfull,
                        const float* __restrict__ hWbias, const float* __restrict__ dinv,
                        __half* __restrict__ hWs, int n_nodes) {
    __shared__ float Wl[64 * 32];
    __shared__ float xs[8 * 64];
    int tid = threadIdx.x;
    for (int idx = tid; idx < 2048; idx += BLK) Wl[idx] = Wfull[idx];
    int rowBase = blockIdx.x * 8;
    for (int idx = tid; idx < 512; idx += BLK) {
        int r = rowBase + (idx >> 6);
        xs[idx] = (r < n_nodes) ? x[(size_t)r * 64 + (idx & 63)] : 0.0f;
    }
    __syncthreads();
    int j = tid & 31, lr = tid >> 5;
    int n = rowBase + lr;
    if (n < n_nodes) {
        float acc = hWbias[j];
#pragma unroll
        for (int k = 0; k < 64; ++k)
            acc += xs[lr * 64 + k] * Wl[k * 32 + j];
        hWs[(size_t)n * 32 + j] = __float2half(dinv[n] * acc);
    }
}

// kD: per-bucket gather-aggregate into LDS tile + relu + run-length pool.
// 16 lanes per edge (half2 per lane), edges independent -> deep MLP.
// acc stride 33 floats: banks (lc+2*j2)%32 -> conflict-free atomics.
__global__ void kD_gather(const int* __restrict__ base_, const int* __restrict__ csrB,
                          const __half2* __restrict__ hws2, const float* __restrict__ dinv,
                          const float* __restrict__ mw, const float* __restrict__ gcn_b,
                          const int* __restrict__ batch, float* __restrict__ pooled,
                          int n_nodes) {
    __shared__ float acc[64 * 33];
    __shared__ float dl[64];
    __shared__ int bl[64];
    int b = blockIdx.x, t = threadIdx.x;
    // init: acc = self hWs row (self-loop weight 1); invalid rows -> 0
    for (int idx = t; idx < 64 * 16; idx += BLK) {
        int lc = idx >> 4, j2 = idx & 15;
        int n = b * 64 + lc;
        float2 f = make_float2(0.0f, 0.0f);
        if (n < n_nodes) f = __half22float2(hws2[(size_t)n * 16 + j2]);
        acc[lc * 33 + 2 * j2]     = f.x;
        acc[lc * 33 + 2 * j2 + 1] = f.y;
    }
    if (t < 64) {
        int n = b * 64 + t;
        dl[t] = (n < n_nodes) ? dinv[n] : 0.0f;
        bl[t] = (n < n_nodes) ? batch[n] : -1;
    }
    __syncthreads();
    float a = mw[0], bb = mw[1], c3 = mw[2];
    float m = fmaxf(a, fmaxf(bb, c3));
    float ea = __expf(a - m), eb = __expf(bb - m), ec = __expf(c3 - m);
    float inv = 1.0f / (ea + eb + ec);
    float w0 = ea * inv, w1 = eb * inv, w2 = ec * inv;
    int p0 = base_[b], p1 = base_[b + 1];
    int g = t >> 4, j2 = t & 15;
    int p = p0 + g;
    for (; p + 16 < p1; p += 32) {       // 2 independent edges in flight
        int eA = csrB[p], eB = csrB[p + 16];
        __half2 vA = hws2[(size_t)((eA >> 2) & 0x1FFFF) * 16 + j2];
        __half2 vB = hws2[(size_t)((eB >> 2) & 0x1FFFF) * 16 + j2];
        int cA = eA & 3, cB = eB & 3;
        float wA = (cA == 0) ? w0 : ((cA == 1) ? w1 : w2);
        float wB = (cB == 0) ? w0 : ((cB == 1) ? w1 : w2);
        float2 fA = __half22float2(vA), fB = __half22float2(vB);
        int lA = eA >> 19, lB = eB >> 19;
        atomicAdd(&acc[lA * 33 + 2 * j2],     wA * fA.x);
        atomicAdd(&acc[lA * 33 + 2 * j2 + 1], wA * fA.y);
        atomicAdd(&acc[lB * 33 + 2 * j2],     wB * fB.x);
        atomicAdd(&acc[lB * 33 + 2 * j2 + 1], wB * fB.y);
    }
    if (p < p1) {
        int eA = csrB[p];
        __half2 vA = hws2[(size_t)((eA >> 2) & 0x1FFFF) * 16 + j2];
        int cA = eA & 3;
        float wA = (cA == 0) ? w0 : ((cA == 1) ? w1 : w2);
        float2 fA = __half22float2(vA);
        int lA = eA >> 19;
        atomicAdd(&acc[lA * 33 + 2 * j2],     wA * fA.x);
        atomicAdd(&acc[lA * 33 + 2 * j2 + 1], wA * fA.y);
    }
    __syncthreads();
    // epilogue: feature j per thread; run-length pool over sorted batch.
    if (t < 32) {
        int j = t;
        float sum = 0.0f; int g0 = bl[0];
        for (int lc = 0; lc < 64; ++lc) {
            if (bl[lc] < 0) break;
            float val = fmaxf(dl[lc] * acc[lc * 33 + j] + gcn_b[j], 0.0f);
            if (bl[lc] != g0) { atomicAdd(&pooled[g0 * 32 + j], sum); sum = 0.0f; g0 = bl[lc]; }
            sum += val;
        }
        if (g0 >= 0) atomicAdd(&pooled[g0 * 32 + j], sum);
    }
}

// k7: head: z = relu(pooled @ fc1_W + fc1_b); out = z @ out_W + out_b
__global__ void k7_head(const float* __restrict__ pooled, const float* __restrict__ fc1_W,
                        const float* __restrict__ fc1_b, const float* __restrict__ out_W,
                        const float* __restrict__ out_b, float* __restrict__ out,
                        int n_graphs) {
    __shared__ float Wl[32 * 32];
    __shared__ float bl[32];
    __shared__ float owl[32];
    int t = threadIdx.x;
    for (int idx = t; idx < 1024; idx += BLK) Wl[idx] = fc1_W[idx];
    if (t < 32) { bl[t] = fc1_b[t]; owl[t] = out_W[t]; }
    __syncthreads();
    if (t < n_graphs) {
        float p[32];
#pragma unroll
        for (int k = 0; k < 32; ++k) p[k] = pooled[t * 32 + k];
        float acc = 0.0f;
        for (int j = 0; j < 32; ++j) {
            float z = bl[j];
#pragma unroll
            for (int k = 0; k < 32; ++k) z += p[k] * Wl[k * 32 + j];
            z = fmaxf(z, 0.0f);
            acc += z * owl[j];
        }
        out[t] = acc + out_b[0];
    }
}

static inline size_t align_up(size_t v, size_t a) { return (v + a - 1) & ~(a - 1); }

extern "C" void kernel_launch(void* const* d_in, const int* in_sizes, int n_in,
                              void* d_out, int out_size, void* d_ws, size_t ws_size,
                              hipStream_t stream) {
    const float* x     = (const float*)d_in[0];
    const int*   ei    = (const int*)d_in[1];
    const int*   batch = (const int*)d_in[2];
    const int*   km    = (const int*)d_in[3];
    const int*   um    = (const int*)d_in[4];
    const int*   om    = (const int*)d_in[5];
    const float* mw    = (const float*)d_in[6];
    const float* emb_W = (const float*)d_in[7];
    const float* emb_b = (const float*)d_in[8];
    const float* gcn_W = (const float*)d_in[9];
    const float* gcn_b = (const float*)d_in[10];
    const float* fc1_W = (const float*)d_in[11];
    const float* fc1_b = (const float*)d_in[12];
    const float* out_W = (const float*)d_in[13];
    const float* out_b = (const float*)d_in[14];

    const int n_nodes  = in_sizes[0] / 64;
    const int n_edges  = in_sizes[1] / 2;
    const int s0 = in_sizes[3], s1 = in_sizes[4], s2 = in_sizes[5];
    const int n_graphs = out_size;  // 256

    const int* row = ei;
    const int* col = ei + n_edges;

    const int NB  = (n_nodes + 63) >> 6;   // 1563 buckets of 64 nodes
    const int nbs = (NB + 7) / 8;          // buckets per XCD slice

    // ---- workspace layout (~28.3 MB) ----
    char* base = (char*)d_ws;
    int*     cnt    = (int*)base;     base += (size_t)NCHUNK * NB * 4;   // 3.2 MB
    int*     offT   = (int*)base;     base += (size_t)NB * NCHUNK * 4;   // 3.2 MB
    int*     tot    = (int*)base;     base += (size_t)NB * 4;
    int*     base_  = (int*)base;     base += (size_t)(NB + 1) * 4;
    float*   dinv   = (float*)base;   base += (size_t)n_nodes * 4;
    float*   pooled = (float*)base;   base += (size_t)n_graphs * 32 * 4;
    float*   Wfull  = (float*)base;   base += 2048 * 4;
    float*   hWbias = (float*)base;   base += 32 * 4;
    uint8_t* ewc    = (uint8_t*)base; base += align_up((size_t)n_edges, 64);
    int*     csrB   = (int*)base;     base += (size_t)n_edges * 4;       // 12 MB
    base = (char*)align_up((size_t)base, 64);
    __half*  hWs    = (__half*)base;  base += (size_t)n_nodes * 32 * 2;  // 6.4 MB

    hipMemsetAsync(pooled, 0, (size_t)n_graphs * 32 * 4, stream);

    k1_cls<<<(s0 + s1 + s2 + BLK - 1) / BLK, BLK, 0, stream>>>(km, um, om, s0, s1, s2, ewc);
    kA_count<<<NCHUNK, BLK, 0, stream>>>(col, cnt, n_edges, NB);
    kB_col<<<NB, BLK, 0, stream>>>(cnt, offT, tot, NB);
    kBase<<<1, BLK, 0, stream>>>(tot, base_, NB);
    kC_scatter<<<NCHUNK * 8, BLK, 0, stream>>>(row, col, ewc, base_, offT, csrB,
                                               n_edges, NB, nbs);
    kDeg<<<NB, BLK, 0, stream>>>(base_, csrB, mw, dinv, n_nodes);
    k3_weights<<<1, BLK, 0, stream>>>(emb_W, emb_b, gcn_W, Wfull, hWbias);
    k4_gemm<<<(n_nodes + 7) / 8, BLK, 0, stream>>>(x, Wfull, hWbias, dinv, hWs, n_nodes);
    kD_gather<<<NB, BLK, 0, stream>>>(base_, csrB, (const __half2*)hWs, dinv, mw,
                                      gcn_b, batch, pooled, n_nodes);
    k7_head<<<1, BLK, 0, stream>>>(pooled, fc1_W, fc1_b, out_W, out_b, (float*)d_out, n_graphs);
}

// Round 6
// 483.153 us; speedup vs baseline: 1.7173x; 1.7173x over previous
//
#include <hip/hip_runtime.h>
#include <hip/hip_fp16.h>
#include <stdint.h>

// GCN forward. N=100000, E=3000000, G=256, F_IN=64, NHID=32.
// R1: 96M global scatter-atomics = L2 atomic ceiling (312us) -> gather.
// R2: naive CSR build = 16x write amplification across 8 incoherent L2s.
// R3: XCD-sliced cursor build works but is ~300us (hidden); gather latency-bound.
// R4: fp16 halved gather lines; gather still latency-bound at ~1TB/s effective.
// R5: bucket build with precomputed offsets is cheap (~140us, zero global
//     atomics) BUT 96M LDS float atomics in consumer = 570us. Lesson: LDS
//     atomic pipe ~3.6cyc/op dominates; VALUBusy blind to it.
// R6: R5 build + consumer that counting-sorts each bucket's edges in LDS
//     (6M LDS *int* atomics total) then does per-node register-accumulated
//     gather, 4 loads in flight; pool via direct global atomics (cheap per R4).

#define BLK 256
#define NCHUNK 512          // edge chunks for count/scatter
#define MAXNB 1600          // max buckets (N<=102400)
#define ENTCAP 4096         // per-bucket LDS entry capacity (λ=1920, σ=44)

// K1: edge class from masks (masks exactly cover E; ewc pre-memset to 3).
__global__ void k1_cls(const int* __restrict__ km, const int* __restrict__ um,
                       const int* __restrict__ om, int s0, int s1, int s2,
                       uint8_t* __restrict__ ewc) {
    int i = blockIdx.x * blockDim.x + threadIdx.x;
    int total = s0 + s1 + s2;
    if (i >= total) return;
    int e, cls;
    if (i < s0)           { e = km[i];           cls = 0; }
    else if (i < s0 + s1) { e = um[i - s0];      cls = 1; }
    else                  { e = om[i - s0 - s1]; cls = 2; }
    ewc[e] = (uint8_t)cls;
}

// kA: per-chunk bucket histogram (LDS) + weighted degree accumulation.
// Sequential col/ewc reads; 3M random global f32 atomics on 400KB degf
// (runs at the measured ~308Gops atomic ceiling -> ~10us).
__global__ void kA_count(const int* __restrict__ col, const uint8_t* __restrict__ ewc,
                         const float* __restrict__ mw, int* __restrict__ cnt,
                         float* __restrict__ degf, int n_edges, int NB) {
    __shared__ int lh[MAXNB];
    int t = threadIdx.x, c = blockIdx.x;
    for (int b = t; b < NB; b += BLK) lh[b] = 0;
    __syncthreads();
    float a = mw[0], bb = mw[1], c3 = mw[2];
    float m = fmaxf(a, fmaxf(bb, c3));
    float ea = __expf(a - m), eb = __expf(bb - m), ec = __expf(c3 - m);
    float inv = 1.0f / (ea + eb + ec);
    float w0 = ea * inv, w1 = eb * inv, w2 = ec * inv;
    int chunk = (n_edges + NCHUNK - 1) / NCHUNK;
    int e0 = c * chunk, e1 = min(e0 + chunk, n_edges);
    for (int e = e0 + t; e < e1; e += BLK) {
        int cc = col[e];
        atomicAdd(&lh[cc >> 6], 1);
        int cls = ewc[e] & 3;
        float w = (cls == 0) ? w0 : ((cls == 1) ? w1 : ((cls == 2) ? w2 : 1.0f));
        atomicAdd(&degf[cc], w);
    }
    __syncthreads();
    for (int b = t; b < NB; b += BLK) cnt[(size_t)c * NB + b] = lh[b];
}

// kB: per bucket b, exclusive scan over chunks of cnt[c][b] -> offT[b][c], tot[b].
__global__ void kB_col(const int* __restrict__ cnt, int* __restrict__ offT,
                       int* __restrict__ tot, int NB) {
    __shared__ int s[BLK];
    int b = blockIdx.x, t = threadIdx.x;
    int a0 = cnt[(size_t)(2 * t) * NB + b];
    int a1 = cnt[(size_t)(2 * t + 1) * NB + b];
    s[t] = a0 + a1; __syncthreads();
    for (int st = 1; st < BLK; st <<= 1) {
        int v = (t >= st) ? s[t - st] : 0;
        __syncthreads(); s[t] += v; __syncthreads();
    }
    int ex = (t == 0) ? 0 : s[t - 1];
    offT[(size_t)b * NCHUNK + 2 * t]     = ex;
    offT[(size_t)b * NCHUNK + 2 * t + 1] = ex + a0;
    if (t == BLK - 1) tot[b] = s[BLK - 1];
}

// kBase: single-block exclusive scan of tot[NB] -> base_[0..NB].
__global__ void kBase(const int* __restrict__ tot, int* __restrict__ base_, int NB) {
    __shared__ int s[BLK];
    const int K = 7;  // 256*7 = 1792 >= MAXNB
    int t = threadIdx.x;
    int v[K]; int sum = 0;
#pragma unroll
    for (int k = 0; k < K; ++k) {
        int i = t * K + k;
        v[k] = (i < NB) ? tot[i] : 0;
        sum += v[k];
    }
    s[t] = sum; __syncthreads();
    for (int st = 1; st < BLK; st <<= 1) {
        int x = (t >= st) ? s[t - st] : 0;
        __syncthreads(); s[t] += x; __syncthreads();
    }
    int ex = (t == 0) ? 0 : s[t - 1];
#pragma unroll
    for (int k = 0; k < K; ++k) {
        int i = t * K + k;
        if (i < NB) base_[i] = ex;
        ex += v[k];
    }
    if (t == BLK - 1) base_[NB] = s[BLK - 1];
}

// kC: 4-slice XCD-partitioned scatter into bucket lists. Zero global atomics:
// (chunk c, bucket b) range is exclusive; cursor = base_[b]+offT[b][c] in LDS.
// Entry = (local_col<<19)|(row<<2)|cls.
__global__ void kC_scatter(const int* __restrict__ row, const int* __restrict__ col,
                           const uint8_t* __restrict__ ewc, const int* __restrict__ base_,
                           const int* __restrict__ offT, int* __restrict__ csrB,
                           int n_edges, int NB, int nbs) {
    __shared__ int cur[400];
    int sl = blockIdx.x & 3, c = blockIdx.x >> 2, t = threadIdx.x;
    int b0 = sl * nbs, b1 = min(b0 + nbs, NB);
    for (int b = b0 + t; b < b1; b += BLK)
        cur[b - b0] = base_[b] + offT[(size_t)b * NCHUNK + c];
    __syncthreads();
    int chunk = (n_edges + NCHUNK - 1) / NCHUNK;
    int e0 = c * chunk, e1 = min(e0 + chunk, n_edges);
    for (int e = e0 + t; e < e1; e += BLK) {
        int cc = col[e]; int b = cc >> 6;
        if (b >= b0 && b < b1) {
            int pos = atomicAdd(&cur[b - b0], 1);
            csrB[pos] = ((cc & 63) << 19) | (row[e] << 2) | (ewc[e] & 3);
        }
    }
}

// k3: fold emb through gcn. Grid=8: block g does k-rows [8g,8g+8); block 0 also hWbias.
__global__ void k3_weights(const float* __restrict__ emb_W, const float* __restrict__ emb_b,
                           const float* __restrict__ gcn_W,
                           float* __restrict__ Wfull, float* __restrict__ hWbias) {
    int t = threadIdx.x;
    int k = blockIdx.x * 8 + (t >> 5), j = t & 31;
    float acc;
    if (k == 0) {
        acc = gcn_W[j];
    } else {
        int m = k - 1;
        acc = 0.0f;
#pragma unroll 9
        for (int tt = 0; tt < 63; ++tt)
            acc += emb_W[m * 63 + tt] * gcn_W[(1 + tt) * 32 + j];
    }
    Wfull[k * 32 + j] = acc;
    if (blockIdx.x == 0 && t < 32) {
        float bacc = 0.0f;
        for (int tt = 0; tt < 63; ++tt)
            bacc += emb_b[tt] * gcn_W[(1 + tt) * 32 + t];
        hWbias[t] = bacc;
    }
}

// k4: hWs[n,:] = fp16( rsqrt(degf[n]+1) * (x[n,:] @ Wfull + hWbias) )
__global__ void k4_gemm(const float* __restrict__ x, const float* __restrict__ Wfull,
                        const float* __restrict__ hWbias, const float* __restrict__ degf,
                        __half* __restrict__ hWs, int n_nodes) {
    __shared__ float Wl[64 * 32];
    __shared__ float xs[8 * 64];
    int tid = threadIdx.x;
    for (int idx = tid; idx < 2048; idx += BLK) Wl[idx] = Wfull[idx];
    int rowBase = blockIdx.x * 8;
    for (int idx = tid; idx < 512; idx += BLK) {
        int r = rowBase + (idx >> 6);
        xs[idx] = (r < n_nodes) ? x[(size_t)r * 64 + (idx & 63)] : 0.0f;
    }
    __syncthreads();
    int j = tid & 31, lr = tid >> 5;
    int n = rowBase + lr;
    if (n < n_nodes) {
        float acc = hWbias[j];
#pragma unroll
        for (int k = 0; k < 64; ++k)
            acc += xs[lr * 64 + k] * Wl[k * 32 + j];
        float di = rsqrtf(degf[n] + 1.0f);
        hWs[(size_t)n * 32 + j] = __float2half(di * acc);
    }
}

// kD: per-bucket consumer. Counting-sort bucket edges into LDS per-node lists
// (int LDS atomics only), then per-node register gather (16 lanes/node, half2,
// 4 value loads in flight), relu + direct pool atomics.
__global__ void kD_gather(const int* __restrict__ base_, const int* __restrict__ csrB,
                          const __half2* __restrict__ hws2, const float* __restrict__ degf,
                          const float* __restrict__ mw, const float* __restrict__ gcn_b,
                          const int* __restrict__ batch, float* __restrict__ pooled,
                          int n_nodes) {
    __shared__ int ent[ENTCAP];
    __shared__ int ct[64], st[64], cur[64];
    __shared__ float dl[64], gb[32];
    __shared__ int bl[64];
    int b = blockIdx.x, t = threadIdx.x;
    if (t < 64) {
        int n = b * 64 + t;
        ct[t] = 0;
        dl[t] = (n < n_nodes) ? degf[n] : 0.0f;
        bl[t] = (n < n_nodes) ? batch[n] : -1;
    }
    if (t < 32) gb[t] = gcn_b[t];
    __syncthreads();
    int p0 = base_[b], p1 = base_[b + 1];
    int m = min(p1 - p0, ENTCAP);     // clamp (never hit: 26+ sigma)
    int p1c = p0 + m;
    // pass 1: per-node counts
    for (int p = p0 + t; p < p1c; p += BLK) atomicAdd(&ct[csrB[p] >> 19], 1);
    __syncthreads();
    // exclusive scan of ct[64] -> st (Hillis-Steele on inclusive, then shift)
    if (t < 64) st[t] = ct[t];
    __syncthreads();
    for (int off = 1; off < 64; off <<= 1) {
        int v = (t < 64 && t >= off) ? st[t - off] : 0;
        __syncthreads();
        if (t < 64) st[t] += v;
        __syncthreads();
    }
    if (t < 64) { st[t] -= ct[t]; cur[t] = st[t]; }
    __syncthreads();
    // pass 2: place entries (csrB chunk is L2-hot from pass 1)
    for (int p = p0 + t; p < p1c; p += BLK) {
        int e = csrB[p];
        int pos = atomicAdd(&cur[e >> 19], 1);
        ent[pos] = e;
    }
    __syncthreads();
    // softmax weights
    float a = mw[0], bb = mw[1], c3 = mw[2];
    float mx = fmaxf(a, fmaxf(bb, c3));
    float ea = __expf(a - mx), eb = __expf(bb - mx), ec = __expf(c3 - mx);
    float inv = 1.0f / (ea + eb + ec);
    float w0 = ea * inv, w1 = eb * inv, w2 = ec * inv;
    // pass 3: per-node gather. 16 lanes/node, 4 nodes per group serially.
    int grp = t >> 4, j2 = t & 15;
#pragma unroll
    for (int idx = 0; idx < 4; ++idx) {
        int lc = grp + 16 * idx;
        int n = b * 64 + lc;
        if (n >= n_nodes) continue;
        int s = st[lc], end = s + ct[lc];
        float ax = 0.0f, ay = 0.0f;
        int p = s;
        for (; p + 4 <= end; p += 4) {
            int e0 = ent[p], e1 = ent[p + 1], e2 = ent[p + 2], e3 = ent[p + 3];
            __half2 h0 = hws2[(size_t)((e0 >> 2) & 0x1FFFF) * 16 + j2];
            __half2 h1 = hws2[(size_t)((e1 >> 2) & 0x1FFFF) * 16 + j2];
            __half2 h2 = hws2[(size_t)((e2 >> 2) & 0x1FFFF) * 16 + j2];
            __half2 h3 = hws2[(size_t)((e3 >> 2) & 0x1FFFF) * 16 + j2];
            int c0 = e0 & 3, c1 = e1 & 3, c2 = e2 & 3, c33 = e3 & 3;
            float f0 = (c0 == 0) ? w0 : ((c0 == 1) ? w1 : w2);
            float f1 = (c1 == 0) ? w0 : ((c1 == 1) ? w1 : w2);
            float f2 = (c2 == 0) ? w0 : ((c2 == 1) ? w1 : w2);
            float f3 = (c33 == 0) ? w0 : ((c33 == 1) ? w1 : w2);
            float2 g0 = __half22float2(h0), g1 = __half22float2(h1);
            float2 g2 = __half22float2(h2), g3 = __half22float2(h3);
            ax += f0 * g0.x + f1 * g1.x + f2 * g2.x + f3 * g3.x;
            ay += f0 * g0.y + f1 * g1.y + f2 * g2.y + f3 * g3.y;
        }
        for (; p < end; ++p) {
            int e0 = ent[p];
            __half2 h0 = hws2[(size_t)((e0 >> 2) & 0x1FFFF) * 16 + j2];
            int c0 = e0 & 3;
            float f0 = (c0 == 0) ? w0 : ((c0 == 1) ? w1 : w2);
            float2 g0 = __half22float2(h0);
            ax += f0 * g0.x; ay += f0 * g0.y;
        }
        float2 self = __half22float2(hws2[(size_t)n * 16 + j2]);
        float di = rsqrtf(dl[lc] + 1.0f);
        float rx = fmaxf(di * (ax + self.x) + gb[2 * j2], 0.0f);
        float ry = fmaxf(di * (ay + self.y) + gb[2 * j2 + 1], 0.0f);
        int g = bl[lc];
        atomicAdd(&pooled[g * 32 + 2 * j2], rx);
        atomicAdd(&pooled[g * 32 + 2 * j2 + 1], ry);
    }
}

// k7: head: z = relu(pooled @ fc1_W + fc1_b); out = z @ out_W + out_b
__global__ void k7_head(const float* __restrict__ pooled, const float* __restrict__ fc1_W,
                        const float* __restrict__ fc1_b, const float* __restrict__ out_W,
                        const float* __restrict__ out_b, float* __restrict__ out,
                        int n_graphs) {
    __shared__ float Wl[32 * 32];
    __shared__ float bl[32];
    __shared__ float owl[32];
    int t = threadIdx.x;
    for (int idx = t; idx < 1024; idx += BLK) Wl[idx] = fc1_W[idx];
    if (t < 32) { bl[t] = fc1_b[t]; owl[t] = out_W[t]; }
    __syncthreads();
    if (t < n_graphs) {
        float p[32];
#pragma unroll
        for (int k = 0; k < 32; ++k) p[k] = pooled[t * 32 + k];
        float acc = 0.0f;
        for (int j = 0; j < 32; ++j) {
            float z = bl[j];
#pragma unroll
            for (int k = 0; k < 32; ++k) z += p[k] * Wl[k * 32 + j];
            z = fmaxf(z, 0.0f);
            acc += z * owl[j];
        }
        out[t] = acc + out_b[0];
    }
}

static inline size_t align_up(size_t v, size_t a) { return (v + a - 1) & ~(a - 1); }

extern "C" void kernel_launch(void* const* d_in, const int* in_sizes, int n_in,
                              void* d_out, int out_size, void* d_ws, size_t ws_size,
                              hipStream_t stream) {
    const float* x     = (const float*)d_in[0];
    const int*   ei    = (const int*)d_in[1];
    const int*   batch = (const int*)d_in[2];
    const int*   km    = (const int*)d_in[3];
    const int*   um    = (const int*)d_in[4];
    const int*   om    = (const int*)d_in[5];
    const float* mw    = (const float*)d_in[6];
    const float* emb_W = (const float*)d_in[7];
    const float* emb_b = (const float*)d_in[8];
    const float* gcn_W = (const float*)d_in[9];
    const float* gcn_b = (const float*)d_in[10];
    const float* fc1_W = (const float*)d_in[11];
    const float* fc1_b = (const float*)d_in[12];
    const float* out_W = (const float*)d_in[13];
    const float* out_b = (const float*)d_in[14];

    const int n_nodes  = in_sizes[0] / 64;
    const int n_edges  = in_sizes[1] / 2;
    const int s0 = in_sizes[3], s1 = in_sizes[4], s2 = in_sizes[5];
    const int n_graphs = out_size;  // 256

    const int* row = ei;
    const int* col = ei + n_edges;

    const int NB  = (n_nodes + 63) >> 6;   // 1563 buckets of 64 nodes
    const int nbs = (NB + 3) / 4;          // buckets per slice (4 slices)

    // ---- workspace layout (~28.3 MB) ----
    char* base = (char*)d_ws;
    float*   degf   = (float*)base;   base += (size_t)n_nodes * 4;        // } zeroed
    float*   pooled = (float*)base;   base += (size_t)n_graphs * 32 * 4;  // } together
    int*     cnt    = (int*)base;     base += (size_t)NCHUNK * NB * 4;    // 3.2 MB
    int*     offT   = (int*)base;     base += (size_t)NB * NCHUNK * 4;    // 3.2 MB
    int*     tot    = (int*)base;     base += (size_t)NB * 4;
    int*     base_  = (int*)base;     base += (size_t)(NB + 1) * 4;
    float*   Wfull  = (float*)base;   base += 2048 * 4;
    float*   hWbias = (float*)base;   base += 32 * 4;
    uint8_t* ewc    = (uint8_t*)base; base += align_up((size_t)n_edges, 64);
    int*     csrB   = (int*)base;     base += (size_t)n_edges * 4;        // 12 MB
    base = (char*)align_up((size_t)base, 64);
    __half*  hWs    = (__half*)base;  base += (size_t)n_nodes * 32 * 2;   // 6.4 MB

    hipMemsetAsync(degf, 0, ((size_t)n_nodes + (size_t)n_graphs * 32) * 4, stream);
    hipMemsetAsync(ewc, 3, (size_t)n_edges, stream);   // default class 3 (w=1)

    k1_cls<<<(s0 + s1 + s2 + BLK - 1) / BLK, BLK, 0, stream>>>(km, um, om, s0, s1, s2, ewc);
    kA_count<<<NCHUNK, BLK, 0, stream>>>(col, ewc, mw, cnt, degf, n_edges, NB);
    kB_col<<<NB, BLK, 0, stream>>>(cnt, offT, tot, NB);
    kBase<<<1, BLK, 0, stream>>>(tot, base_, NB);
    kC_scatter<<<NCHUNK * 4, BLK, 0, stream>>>(row, col, ewc, base_, offT, csrB,
                                               n_edges, NB, nbs);
    k3_weights<<<8, BLK, 0, stream>>>(emb_W, emb_b, gcn_W, Wfull, hWbias);
    k4_gemm<<<(n_nodes + 7) / 8, BLK, 0, stream>>>(x, Wfull, hWbias, degf, hWs, n_nodes);
    kD_gather<<<NB, BLK, 0, stream>>>(base_, csrB, (const __half2*)hWs, degf, mw,
                                      gcn_b, batch, pooled, n_nodes);
    k7_head<<<1, BLK, 0, stream>>>(pooled, fc1_W, fc1_b, out_W, out_b, (float*)d_out, n_graphs);
}

// Round 7
// 301.375 us; speedup vs baseline: 2.7531x; 1.6032x over previous
//
#include <hip/hip_runtime.h>
#include <hip/hip_fp16.h>
#include <stdint.h>

// GCN forward. N=100000, E=3000000, G=256, F_IN=64, NHID=32.
// R1: 96M global scatter-atomics = L2 atomic ceiling (312us) -> gather.
// R2: naive CSR build = 16x write amplification across 8 incoherent L2s.
// R3: XCD-sliced cursor build; gather latency-bound.
// R4: fp16 halved gather lines; still latency-bound; build cost hidden.
// R5: precomputed-offset bucket build is cheap; 96M LDS *float* atomics = 570us.
// R6: counting-sort kD works (483us). NEW LESSON: 3M device atomics into a
//     SMALL (400KB) shared array = 156us @ 32B HBM write per op (line
//     ping-pong through the coherent point). Small hot atomic targets are
//     poison; large ones (12.8MB, R1) wrote only 4B/op.
// R7: zero global atomics except ~60K run-length pool adds. Degree counted
//     per-bucket from csrB with LDS int atomics.

#define BLK 256
#define NCHUNK 512          // edge chunks for count/scatter
#define MAXNB 1600          // max buckets (N<=102400)
#define ENTCAP 2560         // per-bucket LDS entries (lambda=1920, 14 sigma)

// K1: edge class from masks (masks exactly cover E; ewc pre-memset to 3).
__global__ void k1_cls(const int* __restrict__ km, const int* __restrict__ um,
                       const int* __restrict__ om, int s0, int s1, int s2,
                       uint8_t* __restrict__ ewc) {
    int i = blockIdx.x * blockDim.x + threadIdx.x;
    int total = s0 + s1 + s2;
    if (i >= total) return;
    int e, cls;
    if (i < s0)           { e = km[i];           cls = 0; }
    else if (i < s0 + s1) { e = um[i - s0];      cls = 1; }
    else                  { e = om[i - s0 - s1]; cls = 2; }
    ewc[e] = (uint8_t)cls;
}

// kA: per-chunk bucket histogram (pure LDS, no global atomics).
__global__ void kA_count(const int* __restrict__ col, int* __restrict__ cnt,
                         int n_edges, int NB) {
    __shared__ int lh[MAXNB];
    int t = threadIdx.x, c = blockIdx.x;
    for (int b = t; b < NB; b += BLK) lh[b] = 0;
    __syncthreads();
    int chunk = (n_edges + NCHUNK - 1) / NCHUNK;
    int e0 = c * chunk, e1 = min(e0 + chunk, n_edges);
    for (int e = e0 + t; e < e1; e += BLK) atomicAdd(&lh[col[e] >> 6], 1);
    __syncthreads();
    for (int b = t; b < NB; b += BLK) cnt[(size_t)c * NB + b] = lh[b];
}

// kB: per bucket b, exclusive scan over chunks of cnt[c][b] -> offT[b][c], tot[b].
__global__ void kB_col(const int* __restrict__ cnt, int* __restrict__ offT,
                       int* __restrict__ tot, int NB) {
    __shared__ int s[BLK];
    int b = blockIdx.x, t = threadIdx.x;
    int a0 = cnt[(size_t)(2 * t) * NB + b];
    int a1 = cnt[(size_t)(2 * t + 1) * NB + b];
    s[t] = a0 + a1; __syncthreads();
    for (int st = 1; st < BLK; st <<= 1) {
        int v = (t >= st) ? s[t - st] : 0;
        __syncthreads(); s[t] += v; __syncthreads();
    }
    int ex = (t == 0) ? 0 : s[t - 1];
    offT[(size_t)b * NCHUNK + 2 * t]     = ex;
    offT[(size_t)b * NCHUNK + 2 * t + 1] = ex + a0;
    if (t == BLK - 1) tot[b] = s[BLK - 1];
}

// kBase: single-block exclusive scan of tot[NB] -> base_[0..NB].
__global__ void kBase(const int* __restrict__ tot, int* __restrict__ base_, int NB) {
    __shared__ int s[BLK];
    const int K = 7;  // 256*7 = 1792 >= MAXNB
    int t = threadIdx.x;
    int v[K]; int sum = 0;
#pragma unroll
    for (int k = 0; k < K; ++k) {
        int i = t * K + k;
        v[k] = (i < NB) ? tot[i] : 0;
        sum += v[k];
    }
    s[t] = sum; __syncthreads();
    for (int st = 1; st < BLK; st <<= 1) {
        int x = (t >= st) ? s[t - st] : 0;
        __syncthreads(); s[t] += x; __syncthreads();
    }
    int ex = (t == 0) ? 0 : s[t - 1];
#pragma unroll
    for (int k = 0; k < K; ++k) {
        int i = t * K + k;
        if (i < NB) base_[i] = ex;
        ex += v[k];
    }
    if (t == BLK - 1) base_[NB] = s[BLK - 1];
}

// kC: 4-slice XCD-partitioned scatter into bucket lists. Zero global atomics:
// (chunk c, bucket b) range is exclusive; cursor = base_[b]+offT[b][c] in LDS.
// Entry = (local_col<<19)|(row<<2)|cls.
__global__ void kC_scatter(const int* __restrict__ row, const int* __restrict__ col,
                           const uint8_t* __restrict__ ewc, const int* __restrict__ base_,
                           const int* __restrict__ offT, int* __restrict__ csrB,
                           int n_edges, int NB, int nbs) {
    __shared__ int cur[400];
    int sl = blockIdx.x & 3, c = blockIdx.x >> 2, t = threadIdx.x;
    int b0 = sl * nbs, b1 = min(b0 + nbs, NB);
    for (int b = b0 + t; b < b1; b += BLK)
        cur[b - b0] = base_[b] + offT[(size_t)b * NCHUNK + c];
    __syncthreads();
    int chunk = (n_edges + NCHUNK - 1) / NCHUNK;
    int e0 = c * chunk, e1 = min(e0 + chunk, n_edges);
    for (int e = e0 + t; e < e1; e += BLK) {
        int cc = col[e]; int b = cc >> 6;
        if (b >= b0 && b < b1) {
            int pos = atomicAdd(&cur[b - b0], 1);
            csrB[pos] = ((cc & 63) << 19) | (row[e] << 2) | (ewc[e] & 3);
        }
    }
}

// kDeg: per-bucket class counts from csrB (LDS int atomics) -> dinv (coalesced).
__global__ void kDeg(const int* __restrict__ base_, const int* __restrict__ csrB,
                     const float* __restrict__ mw, float* __restrict__ dinv,
                     int n_nodes) {
    __shared__ int ct4[256];   // [lc*4 + cls]
    int b = blockIdx.x, t = threadIdx.x;
    if (t < 256) ct4[t] = 0;
    __syncthreads();
    int p0 = base_[b], p1 = base_[b + 1];
    for (int p = p0 + t; p < p1; p += BLK) {
        int e = csrB[p];
        atomicAdd(&ct4[((e >> 19) << 2) | (e & 3)], 1);
    }
    __syncthreads();
    if (t < 64) {
        int n = b * 64 + t;
        if (n < n_nodes) {
            float a = mw[0], bb = mw[1], c3 = mw[2];
            float m = fmaxf(a, fmaxf(bb, c3));
            float ea = __expf(a - m), eb = __expf(bb - m), ec = __expf(c3 - m);
            float inv = 1.0f / (ea + eb + ec);
            float deg = (ea * inv) * (float)ct4[t * 4]
                      + (eb * inv) * (float)ct4[t * 4 + 1]
                      + (ec * inv) * (float)ct4[t * 4 + 2]
                      + (float)ct4[t * 4 + 3]      // defensive class-3 (w=1)
                      + 1.0f;                       // self-loop
            dinv[n] = rsqrtf(deg);
        }
    }
}

// k3: fold emb through gcn. Grid=8: block g does k-rows [8g,8g+8); block 0 also hWbias.
__global__ void k3_weights(const float* __restrict__ emb_W, const float* __restrict__ emb_b,
                           const float* __restrict__ gcn_W,
                           float* __restrict__ Wfull, float* __restrict__ hWbias) {
    int t = threadIdx.x;
    int k = blockIdx.x * 8 + (t >> 5), j = t & 31;
    float acc;
    if (k == 0) {
        acc = gcn_W[j];
    } else {
        int m = k - 1;
        acc = 0.0f;
#pragma unroll 9
        for (int tt = 0; tt < 63; ++tt)
            acc += emb_W[m * 63 + tt] * gcn_W[(1 + tt) * 32 + j];
    }
    Wfull[k * 32 + j] = acc;
    if (blockIdx.x == 0 && t < 32) {
        float bacc = 0.0f;
        for (int tt = 0; tt < 63; ++tt)
            bacc += emb_b[tt] * gcn_W[(1 + tt) * 32 + t];
        hWbias[t] = bacc;
    }
}

// k4: hWs[n,:] = fp16( dinv[n] * (x[n,:] @ Wfull + hWbias) )
__global__ void k4_gemm(const float* __restrict__ x, const float* __restrict__ Wfull,
                        const float* __restrict__ hWbias, const float* __restrict__ dinv,
                        __half* __restrict__ hWs, int n_nodes) {
    __shared__ float Wl[64 * 32];
    __shared__ float xs[8 * 64];
    int tid = threadIdx.x;
    for (int idx = tid; idx < 2048; idx += BLK) Wl[idx] = Wfull[idx];
    int rowBase = blockIdx.x * 8;
    for (int idx = tid; idx < 512; idx += BLK) {
        int r = rowBase + (idx >> 6);
        xs[idx] = (r < n_nodes) ? x[(size_t)r * 64 + (idx & 63)] : 0.0f;
    }
    __syncthreads();
    int j = tid & 31, lr = tid >> 5;
    int n = rowBase + lr;
    if (n < n_nodes) {
        float acc = hWbias[j];
#pragma unroll
        for (int k = 0; k < 64; ++k)
            acc += xs[lr * 64 + k] * Wl[k * 32 + j];
        hWs[(size_t)n * 32 + j] = __float2half(dinv[n] * acc);
    }
}

// kD: per-bucket consumer. Counting-sort edges into LDS per-node lists (int
// atomics), per-node register gather (16 lanes/node, half2, 4 loads in
// flight), relu into LDS tile, run-length pool (few atomics per bucket).
__global__ void kD_gather(const int* __restrict__ base_, const int* __restrict__ csrB,
                          const __half2* __restrict__ hws2, const float* __restrict__ dinv,
                          const float* __restrict__ mw, const float* __restrict__ gcn_b,
                          const int* __restrict__ batch, float* __restrict__ pooled,
                          int n_nodes) {
    __shared__ int ent[ENTCAP];
    __shared__ float res[64 * 33];
    __shared__ int ct[64], st[64], cur[64];
    __shared__ float dl[64], gb[32];
    __shared__ int bl[64];
    int b = blockIdx.x, t = threadIdx.x;
    if (t < 64) {
        int n = b * 64 + t;
        ct[t] = 0;
        dl[t] = (n < n_nodes) ? dinv[n] : 0.0f;
        bl[t] = (n < n_nodes) ? batch[n] : -1;
    }
    if (t < 32) gb[t] = gcn_b[t];
    __syncthreads();
    int p0 = base_[b], p1 = base_[b + 1];
    int m = min(p1 - p0, ENTCAP);     // clamp (14 sigma margin, never hit)
    int p1c = p0 + m;
    // pass 1: per-node counts
    for (int p = p0 + t; p < p1c; p += BLK) atomicAdd(&ct[csrB[p] >> 19], 1);
    __syncthreads();
    // exclusive scan of ct[64]
    if (t < 64) st[t] = ct[t];
    __syncthreads();
    for (int off = 1; off < 64; off <<= 1) {
        int v = (t < 64 && t >= off) ? st[t - off] : 0;
        __syncthreads();
        if (t < 64) st[t] += v;
        __syncthreads();
    }
    if (t < 64) { st[t] -= ct[t]; cur[t] = st[t]; }
    __syncthreads();
    // pass 2: place entries (csrB chunk L2-hot from pass 1)
    for (int p = p0 + t; p < p1c; p += BLK) {
        int e = csrB[p];
        int pos = atomicAdd(&cur[e >> 19], 1);
        ent[pos] = e;
    }
    __syncthreads();
    // softmax weights
    float a = mw[0], bb = mw[1], c3 = mw[2];
    float mx = fmaxf(a, fmaxf(bb, c3));
    float ea = __expf(a - mx), eb = __expf(bb - mx), ec = __expf(c3 - mx);
    float inv = 1.0f / (ea + eb + ec);
    float w0 = ea * inv, w1 = eb * inv, w2 = ec * inv;
    // pass 3: per-node gather, result -> res tile (stride 33: conflict-free)
    int grp = t >> 4, j2 = t & 15;
#pragma unroll
    for (int idx = 0; idx < 4; ++idx) {
        int lc = grp + 16 * idx;
        int n = b * 64 + lc;
        float rx = 0.0f, ry = 0.0f;
        if (n < n_nodes) {
            int s = st[lc], end = s + ct[lc];
            float ax = 0.0f, ay = 0.0f;
            int p = s;
            for (; p + 4 <= end; p += 4) {
                int e0 = ent[p], e1 = ent[p + 1], e2 = ent[p + 2], e3 = ent[p + 3];
                __half2 h0 = hws2[(size_t)((e0 >> 2) & 0x1FFFF) * 16 + j2];
                __half2 h1 = hws2[(size_t)((e1 >> 2) & 0x1FFFF) * 16 + j2];
                __half2 h2 = hws2[(size_t)((e2 >> 2) & 0x1FFFF) * 16 + j2];
                __half2 h3 = hws2[(size_t)((e3 >> 2) & 0x1FFFF) * 16 + j2];
                int c0 = e0 & 3, c1 = e1 & 3, c2 = e2 & 3, c33 = e3 & 3;
                float f0 = (c0 == 0) ? w0 : ((c0 == 1) ? w1 : w2);
                float f1 = (c1 == 0) ? w0 : ((c1 == 1) ? w1 : w2);
                float f2 = (c2 == 0) ? w0 : ((c2 == 1) ? w1 : w2);
                float f3 = (c33 == 0) ? w0 : ((c33 == 1) ? w1 : w2);
                float2 g0 = __half22float2(h0), g1 = __half22float2(h1);
                float2 g2 = __half22float2(h2), g3 = __half22float2(h3);
                ax += f0 * g0.x + f1 * g1.x + f2 * g2.x + f3 * g3.x;
                ay += f0 * g0.y + f1 * g1.y + f2 * g2.y + f3 * g3.y;
            }
            for (; p < end; ++p) {
                int e0 = ent[p];
                __half2 h0 = hws2[(size_t)((e0 >> 2) & 0x1FFFF) * 16 + j2];
                int c0 = e0 & 3;
                float f0 = (c0 == 0) ? w0 : ((c0 == 1) ? w1 : w2);
                float2 g0 = __half22float2(h0);
                ax += f0 * g0.x; ay += f0 * g0.y;
            }
            float2 self = __half22float2(hws2[(size_t)n * 16 + j2]);
            float di = dl[lc];
            rx = fmaxf(di * (ax + self.x) + gb[2 * j2], 0.0f);
            ry = fmaxf(di * (ay + self.y) + gb[2 * j2 + 1], 0.0f);
        }
        res[lc * 33 + 2 * j2]     = rx;
        res[lc * 33 + 2 * j2 + 1] = ry;
    }
    __syncthreads();
    // run-length pool over sorted batch: ~1-2 graphs per bucket.
    if (t < 32) {
        int j = t;
        float sum = 0.0f; int g0 = bl[0];
        for (int lc = 0; lc < 64; ++lc) {
            if (bl[lc] < 0) break;
            float val = res[lc * 33 + j];
            if (bl[lc] != g0) { atomicAdd(&pooled[g0 * 32 + j], sum); sum = 0.0f; g0 = bl[lc]; }
            sum += val;
        }
        if (g0 >= 0) atomicAdd(&pooled[g0 * 32 + j], sum);
    }
}

// k7: head: z = relu(pooled @ fc1_W + fc1_b); out = z @ out_W + out_b
__global__ void k7_head(const float* __restrict__ pooled, const float* __restrict__ fc1_W,
                        const float* __restrict__ fc1_b, const float* __restrict__ out_W,
                        const float* __restrict__ out_b, float* __restrict__ out,
                        int n_graphs) {
    __shared__ float Wl[32 * 32];
    __shared__ float bl[32];
    __shared__ float owl[32];
    int t = threadIdx.x;
    for (int idx = t; idx < 1024; idx += BLK) Wl[idx] = fc1_W[idx];
    if (t < 32) { bl[t] = fc1_b[t]; owl[t] = out_W[t]; }
    __syncthreads();
    if (t < n_graphs) {
        float p[32];
#pragma unroll
        for (int k = 0; k < 32; ++k) p[k] = pooled[t * 32 + k];
        float acc = 0.0f;
        for (int j = 0; j < 32; ++j) {
            float z = bl[j];
#pragma unroll
            for (int k = 0; k < 32; ++k) z += p[k] * Wl[k * 32 + j];
            z = fmaxf(z, 0.0f);
            acc += z * owl[j];
        }
        out[t] = acc + out_b[0];
    }
}

static inline size_t align_up(size_t v, size_t a) { return (v + a - 1) & ~(a - 1); }

extern "C" void kernel_launch(void* const* d_in, const int* in_sizes, int n_in,
                              void* d_out, int out_size, void* d_ws, size_t ws_size,
                              hipStream_t stream) {
    const float* x     = (const float*)d_in[0];
    const int*   ei    = (const int*)d_in[1];
    const int*   batch = (const int*)d_in[2];
    const int*   km    = (const int*)d_in[3];
    const int*   um    = (const int*)d_in[4];
    const int*   om    = (const int*)d_in[5];
    const float* mw    = (const float*)d_in[6];
    const float* emb_W = (const float*)d_in[7];
    const float* emb_b = (const float*)d_in[8];
    const float* gcn_W = (const float*)d_in[9];
    const float* gcn_b = (const float*)d_in[10];
    const float* fc1_W = (const float*)d_in[11];
    const float* fc1_b = (const float*)d_in[12];
    const float* out_W = (const float*)d_in[13];
    const float* out_b = (const float*)d_in[14];

    const int n_nodes  = in_sizes[0] / 64;
    const int n_edges  = in_sizes[1] / 2;
    const int s0 = in_sizes[3], s1 = in_sizes[4], s2 = in_sizes[5];
    const int n_graphs = out_size;  // 256

    const int* row = ei;
    const int* col = ei + n_edges;

    const int NB  = (n_nodes + 63) >> 6;   // 1563 buckets of 64 nodes
    const int nbs = (NB + 3) / 4;          // buckets per slice (4 slices)

    // ---- workspace layout (~28.3 MB) ----
    char* base = (char*)d_ws;
    float*   dinv   = (float*)base;   base += (size_t)n_nodes * 4;
    float*   pooled = (float*)base;   base += (size_t)n_graphs * 32 * 4;   // zeroed
    int*     cnt    = (int*)base;     base += (size_t)NCHUNK * NB * 4;     // 3.2 MB
    int*     offT   = (int*)base;     base += (size_t)NB * NCHUNK * 4;     // 3.2 MB
    int*     tot    = (int*)base;     base += (size_t)NB * 4;
    int*     base_  = (int*)base;     base += (size_t)(NB + 1) * 4;
    float*   Wfull  = (float*)base;   base += 2048 * 4;
    float*   hWbias = (float*)base;   base += 32 * 4;
    uint8_t* ewc    = (uint8_t*)base; base += align_up((size_t)n_edges, 64);
    int*     csrB   = (int*)base;     base += (size_t)n_edges * 4;         // 12 MB
    base = (char*)align_up((size_t)base, 64);
    __half*  hWs    = (__half*)base;  base += (size_t)n_nodes * 32 * 2;    // 6.4 MB

    hipMemsetAsync(pooled, 0, (size_t)n_graphs * 32 * 4, stream);
    hipMemsetAsync(ewc, 3, (size_t)n_edges, stream);   // default class 3 (w=1)

    k1_cls<<<(s0 + s1 + s2 + BLK - 1) / BLK, BLK, 0, stream>>>(km, um, om, s0, s1, s2, ewc);
    kA_count<<<NCHUNK, BLK, 0, stream>>>(col, cnt, n_edges, NB);
    kB_col<<<NB, BLK, 0, stream>>>(cnt, offT, tot, NB);
    kBase<<<1, BLK, 0, stream>>>(tot, base_, NB);
    kC_scatter<<<NCHUNK * 4, BLK, 0, stream>>>(row, col, ewc, base_, offT, csrB,
                                               n_edges, NB, nbs);
    kDeg<<<NB, BLK, 0, stream>>>(base_, csrB, mw, dinv, n_nodes);
    k3_weights<<<8, BLK, 0, stream>>>(emb_W, emb_b, gcn_W, Wfull, hWbias);
    k4_gemm<<<(n_nodes + 7) / 8, BLK, 0, stream>>>(x, Wfull, hWbias, dinv, hWs, n_nodes);
    kD_gather<<<NB, BLK, 0, stream>>>(base_, csrB, (const __half2*)hWs, dinv, mw,
                                      gcn_b, batch, pooled, n_nodes);
    k7_head<<<1, BLK, 0, stream>>>(pooled, fc1_W, fc1_b, out_W, out_b, (float*)d_out, n_graphs);
}

// Round 8
// 289.365 us; speedup vs baseline: 2.8674x; 1.0415x over previous
//
#include <hip/hip_runtime.h>
#include <hip/hip_fp16.h>
#include <stdint.h>

// GCN forward. N=100000, E=3000000, G=256, F_IN=64, NHID=32.
// R1: 96M global scatter-atomics = L2 atomic ceiling (312us) -> gather.
// R2: naive CSR build = 16x write amplification across 8 incoherent L2s.
// R3: 8-slice XCD build clean; gather latency-bound.
// R4: fp16 halved gather lines; still latency-bound.
// R5: 96M LDS *float* atomics = 570us. LDS atomic pipe ~3.6cyc/op.
// R6: counting-sort consumer works. Small hot global atomic arrays are
//     poison (32B HBM line ping-pong per op); large arrays write 4B/op.
// R7: 301us. kC 4-slice regression: slice=blockIdx&3 maps each csrB region
//     to TWO XCDs -> partial-line ping-pong again (WRITE 120MB for 12MB).
// R8: kC back to 8 slices (one XCD per region; L3 absorbs the re-reads,
//     proven by R7 FETCH=56MB). kD 8-deep load pipeline. No ewc memset.

#define BLK 256
#define NCHUNK 512          // edge chunks for count/scatter
#define MAXNB 1600          // max buckets (N<=102400)
#define ENTCAP 2560         // per-bucket LDS entries (lambda=1920, 14 sigma)

// K1: edge class from masks (masks exactly cover E: s0+s1+s2 == E).
__global__ void k1_cls(const int* __restrict__ km, const int* __restrict__ um,
                       const int* __restrict__ om, int s0, int s1, int s2,
                       uint8_t* __restrict__ ewc) {
    int i = blockIdx.x * blockDim.x + threadIdx.x;
    int total = s0 + s1 + s2;
    if (i >= total) return;
    int e, cls;
    if (i < s0)           { e = km[i];           cls = 0; }
    else if (i < s0 + s1) { e = um[i - s0];      cls = 1; }
    else                  { e = om[i - s0 - s1]; cls = 2; }
    ewc[e] = (uint8_t)cls;
}

// kA: per-chunk bucket histogram (pure LDS, no global atomics).
__global__ void kA_count(const int* __restrict__ col, int* __restrict__ cnt,
                         int n_edges, int NB) {
    __shared__ int lh[MAXNB];
    int t = threadIdx.x, c = blockIdx.x;
    for (int b = t; b < NB; b += BLK) lh[b] = 0;
    __syncthreads();
    int chunk = (n_edges + NCHUNK - 1) / NCHUNK;
    int e0 = c * chunk, e1 = min(e0 + chunk, n_edges);
    for (int e = e0 + t; e < e1; e += BLK) atomicAdd(&lh[col[e] >> 6], 1);
    __syncthreads();
    for (int b = t; b < NB; b += BLK) cnt[(size_t)c * NB + b] = lh[b];
}

// kB: per bucket b, exclusive scan over chunks of cnt[c][b] -> offT[b][c], tot[b].
__global__ void kB_col(const int* __restrict__ cnt, int* __restrict__ offT,
                       int* __restrict__ tot, int NB) {
    __shared__ int s[BLK];
    int b = blockIdx.x, t = threadIdx.x;
    int a0 = cnt[(size_t)(2 * t) * NB + b];
    int a1 = cnt[(size_t)(2 * t + 1) * NB + b];
    s[t] = a0 + a1; __syncthreads();
    for (int st = 1; st < BLK; st <<= 1) {
        int v = (t >= st) ? s[t - st] : 0;
        __syncthreads(); s[t] += v; __syncthreads();
    }
    int ex = (t == 0) ? 0 : s[t - 1];
    offT[(size_t)b * NCHUNK + 2 * t]     = ex;
    offT[(size_t)b * NCHUNK + 2 * t + 1] = ex + a0;
    if (t == BLK - 1) tot[b] = s[BLK - 1];
}

// kBase: single-block exclusive scan of tot[NB] -> base_[0..NB].
__global__ void kBase(const int* __restrict__ tot, int* __restrict__ base_, int NB) {
    __shared__ int s[BLK];
    const int K = 7;  // 256*7 = 1792 >= MAXNB
    int t = threadIdx.x;
    int v[K]; int sum = 0;
#pragma unroll
    for (int k = 0; k < K; ++k) {
        int i = t * K + k;
        v[k] = (i < NB) ? tot[i] : 0;
        sum += v[k];
    }
    s[t] = sum; __syncthreads();
    for (int st = 1; st < BLK; st <<= 1) {
        int x = (t >= st) ? s[t - st] : 0;
        __syncthreads(); s[t] += x; __syncthreads();
    }
    int ex = (t == 0) ? 0 : s[t - 1];
#pragma unroll
    for (int k = 0; k < K; ++k) {
        int i = t * K + k;
        if (i < NB) base_[i] = ex;
        ex += v[k];
    }
    if (t == BLK - 1) base_[NB] = s[BLK - 1];
}

// kC: 8-slice XCD-partitioned scatter into bucket lists. Zero global atomics;
// slice = blockIdx&7 -> exactly ONE XCD owns each csrB region (~1.5MB,
// L2-resident; lines fill completely before eviction). L3 serves re-reads.
// Entry = (local_col<<19)|(row<<2)|cls.
__global__ void kC_scatter(const int* __restrict__ row, const int* __restrict__ col,
                           const uint8_t* __restrict__ ewc, const int* __restrict__ base_,
                           const int* __restrict__ offT, int* __restrict__ csrB,
                           int n_edges, int NB, int nbs) {
    __shared__ int cur[200];
    int sl = blockIdx.x & 7, c = blockIdx.x >> 3, t = threadIdx.x;
    int b0 = sl * nbs, b1 = min(b0 + nbs, NB);
    for (int b = b0 + t; b < b1; b += BLK)
        cur[b - b0] = base_[b] + offT[(size_t)b * NCHUNK + c];
    __syncthreads();
    int chunk = (n_edges + NCHUNK - 1) / NCHUNK;
    int e0 = c * chunk, e1 = min(e0 + chunk, n_edges);
    for (int e = e0 + t; e < e1; e += BLK) {
        int cc = col[e]; int b = cc >> 6;
        if (b >= b0 && b < b1) {
            int pos = atomicAdd(&cur[b - b0], 1);
            csrB[pos] = ((cc & 63) << 19) | (row[e] << 2) | (ewc[e] & 3);
        }
    }
}

// kDeg: per-bucket class counts from csrB (LDS int atomics) -> dinv (coalesced).
__global__ void kDeg(const int* __restrict__ base_, const int* __restrict__ csrB,
                     const float* __restrict__ mw, float* __restrict__ dinv,
                     int n_nodes) {
    __shared__ int ct4[256];   // [lc*4 + cls]
    int b = blockIdx.x, t = threadIdx.x;
    if (t < 256) ct4[t] = 0;
    __syncthreads();
    int p0 = base_[b], p1 = base_[b + 1];
    for (int p = p0 + t; p < p1; p += BLK) {
        int e = csrB[p];
        atomicAdd(&ct4[((e >> 19) << 2) | (e & 3)], 1);
    }
    __syncthreads();
    if (t < 64) {
        int n = b * 64 + t;
        if (n < n_nodes) {
            float a = mw[0], bb = mw[1], c3 = mw[2];
            float m = fmaxf(a, fmaxf(bb, c3));
            float ea = __expf(a - m), eb = __expf(bb - m), ec = __expf(c3 - m);
            float inv = 1.0f / (ea + eb + ec);
            float deg = (ea * inv) * (float)ct4[t * 4]
                      + (eb * inv) * (float)ct4[t * 4 + 1]
                      + (ec * inv) * (float)ct4[t * 4 + 2]
                      + 1.0f;                       // self-loop
            dinv[n] = rsqrtf(deg);
        }
    }
}

// k3: fold emb through gcn. Grid=8: block g does k-rows [8g,8g+8); block 0 also hWbias.
__global__ void k3_weights(const float* __restrict__ emb_W, const float* __restrict__ emb_b,
                           const float* __restrict__ gcn_W,
                           float* __restrict__ Wfull, float* __restrict__ hWbias) {
    int t = threadIdx.x;
    int k = blockIdx.x * 8 + (t >> 5), j = t & 31;
    float acc;
    if (k == 0) {
        acc = gcn_W[j];
    } else {
        int m = k - 1;
        acc = 0.0f;
#pragma unroll 9
        for (int tt = 0; tt < 63; ++tt)
            acc += emb_W[m * 63 + tt] * gcn_W[(1 + tt) * 32 + j];
    }
    Wfull[k * 32 + j] = acc;
    if (blockIdx.x == 0 && t < 32) {
        float bacc = 0.0f;
        for (int tt = 0; tt < 63; ++tt)
            bacc += emb_b[tt] * gcn_W[(1 + tt) * 32 + t];
        hWbias[t] = bacc;
    }
}

// k4: hWs[n,:] = fp16( dinv[n] * (x[n,:] @ Wfull + hWbias) )
__global__ void k4_gemm(const float* __restrict__ x, const float* __restrict__ Wfull,
                        const float* __restrict__ hWbias, const float* __restrict__ dinv,
                        __half* __restrict__ hWs, int n_nodes) {
    __shared__ float Wl[64 * 32];
    __shared__ float xs[8 * 64];
    int tid = threadIdx.x;
    for (int idx = tid; idx < 2048; idx += BLK) Wl[idx] = Wfull[idx];
    int rowBase = blockIdx.x * 8;
    for (int idx = tid; idx < 512; idx += BLK) {
        int r = rowBase + (idx >> 6);
        xs[idx] = (r < n_nodes) ? x[(size_t)r * 64 + (idx & 63)] : 0.0f;
    }
    __syncthreads();
    int j = tid & 31, lr = tid >> 5;
    int n = rowBase + lr;
    if (n < n_nodes) {
        float acc = hWbias[j];
#pragma unroll
        for (int k = 0; k < 64; ++k)
            acc += xs[lr * 64 + k] * Wl[k * 32 + j];
        hWs[(size_t)n * 32 + j] = __float2half(dinv[n] * acc);
    }
}

// kD: per-bucket consumer. Counting-sort edges into LDS per-node lists (int
// atomics), per-node register gather (16 lanes/node, half2, 8 loads in
// flight), relu into LDS tile, run-length pool (few atomics per bucket).
__global__ void kD_gather(const int* __restrict__ base_, const int* __restrict__ csrB,
                          const __half2* __restrict__ hws2, const float* __restrict__ dinv,
                          const float* __restrict__ mw, const float* __restrict__ gcn_b,
                          const int* __restrict__ batch, float* __restrict__ pooled,
                          int n_nodes) {
    __shared__ int ent[ENTCAP];
    __shared__ float res[64 * 33];
    __shared__ int ct[64], st[64], cur[64];
    __shared__ float dl[64], gb[32];
    __shared__ int bl[64];
    int b = blockIdx.x, t = threadIdx.x;
    if (t < 64) {
        int n = b * 64 + t;
        ct[t] = 0;
        dl[t] = (n < n_nodes) ? dinv[n] : 0.0f;
        bl[t] = (n < n_nodes) ? batch[n] : -1;
    }
    if (t < 32) gb[t] = gcn_b[t];
    __syncthreads();
    int p0 = base_[b], p1 = base_[b + 1];
    int m = min(p1 - p0, ENTCAP);     // clamp (14 sigma margin, never hit)
    int p1c = p0 + m;
    // pass 1: per-node counts
    for (int p = p0 + t; p < p1c; p += BLK) atomicAdd(&ct[csrB[p] >> 19], 1);
    __syncthreads();
    // exclusive scan of ct[64]
    if (t < 64) st[t] = ct[t];
    __syncthreads();
    for (int off = 1; off < 64; off <<= 1) {
        int v = (t < 64 && t >= off) ? st[t - off] : 0;
        __syncthreads();
        if (t < 64) st[t] += v;
        __syncthreads();
    }
    if (t < 64) { st[t] -= ct[t]; cur[t] = st[t]; }
    __syncthreads();
    // pass 2: place entries (csrB chunk L2-hot from pass 1)
    for (int p = p0 + t; p < p1c; p += BLK) {
        int e = csrB[p];
        int pos = atomicAdd(&cur[e >> 19], 1);
        ent[pos] = e;
    }
    __syncthreads();
    // softmax weights
    float a = mw[0], bb = mw[1], c3 = mw[2];
    float mx = fmaxf(a, fmaxf(bb, c3));
    float ea = __expf(a - mx), eb = __expf(bb - mx), ec = __expf(c3 - mx);
    float inv = 1.0f / (ea + eb + ec);
    float w0 = ea * inv, w1 = eb * inv, w2 = ec * inv;
    // pass 3: per-node gather, 8 loads in flight, result -> res tile
    int grp = t >> 4, j2 = t & 15;
#pragma unroll
    for (int idx = 0; idx < 4; ++idx) {
        int lc = grp + 16 * idx;
        int n = b * 64 + lc;
        float rx = 0.0f, ry = 0.0f;
        if (n < n_nodes) {
            int s = st[lc], end = s + ct[lc];
            float ax = 0.0f, ay = 0.0f;
            int p = s;
            for (; p + 8 <= end; p += 8) {
                int e0 = ent[p],     e1 = ent[p + 1], e2 = ent[p + 2], e3 = ent[p + 3];
                int e4 = ent[p + 4], e5 = ent[p + 5], e6 = ent[p + 6], e7 = ent[p + 7];
                __half2 h0 = hws2[(size_t)((e0 >> 2) & 0x1FFFF) * 16 + j2];
                __half2 h1 = hws2[(size_t)((e1 >> 2) & 0x1FFFF) * 16 + j2];
                __half2 h2 = hws2[(size_t)((e2 >> 2) & 0x1FFFF) * 16 + j2];
                __half2 h3 = hws2[(size_t)((e3 >> 2) & 0x1FFFF) * 16 + j2];
                __half2 h4 = hws2[(size_t)((e4 >> 2) & 0x1FFFF) * 16 + j2];
                __half2 h5 = hws2[(size_t)((e5 >> 2) & 0x1FFFF) * 16 + j2];
                __half2 h6 = hws2[(size_t)((e6 >> 2) & 0x1FFFF) * 16 + j2];
                __half2 h7 = hws2[(size_t)((e7 >> 2) & 0x1FFFF) * 16 + j2];
                float f0 = ((e0 & 3) == 0) ? w0 : (((e0 & 3) == 1) ? w1 : w2);
                float f1 = ((e1 & 3) == 0) ? w0 : (((e1 & 3) == 1) ? w1 : w2);
                float f2 = ((e2 & 3) == 0) ? w0 : (((e2 & 3) == 1) ? w1 : w2);
                float f3 = ((e3 & 3) == 0) ? w0 : (((e3 & 3) == 1) ? w1 : w2);
                float f4 = ((e4 & 3) == 0) ? w0 : (((e4 & 3) == 1) ? w1 : w2);
                float f5 = ((e5 & 3) == 0) ? w0 : (((e5 & 3) == 1) ? w1 : w2);
                float f6 = ((e6 & 3) == 0) ? w0 : (((e6 & 3) == 1) ? w1 : w2);
                float f7 = ((e7 & 3) == 0) ? w0 : (((e7 & 3) == 1) ? w1 : w2);
                float2 g0 = __half22float2(h0), g1 = __half22float2(h1);
                float2 g2 = __half22float2(h2), g3 = __half22float2(h3);
                float2 g4 = __half22float2(h4), g5 = __half22float2(h5);
                float2 g6 = __half22float2(h6), g7 = __half22float2(h7);
                ax += f0 * g0.x + f1 * g1.x + f2 * g2.x + f3 * g3.x
                    + f4 * g4.x + f5 * g5.x + f6 * g6.x + f7 * g7.x;
                ay += f0 * g0.y + f1 * g1.y + f2 * g2.y + f3 * g3.y
                    + f4 * g4.y + f5 * g5.y + f6 * g6.y + f7 * g7.y;
            }
            for (; p + 4 <= end; p += 4) {
                int e0 = ent[p], e1 = ent[p + 1], e2 = ent[p + 2], e3 = ent[p + 3];
                __half2 h0 = hws2[(size_t)((e0 >> 2) & 0x1FFFF) * 16 + j2];
                __half2 h1 = hws2[(size_t)((e1 >> 2) & 0x1FFFF) * 16 + j2];
                __half2 h2 = hws2[(size_t)((e2 >> 2) & 0x1FFFF) * 16 + j2];
                __half2 h3 = hws2[(size_t)((e3 >> 2) & 0x1FFFF) * 16 + j2];
                float f0 = ((e0 & 3) == 0) ? w0 : (((e0 & 3) == 1) ? w1 : w2);
                float f1 = ((e1 & 3) == 0) ? w0 : (((e1 & 3) == 1) ? w1 : w2);
                float f2 = ((e2 & 3) == 0) ? w0 : (((e2 & 3) == 1) ? w1 : w2);
                float f3 = ((e3 & 3) == 0) ? w0 : (((e3 & 3) == 1) ? w1 : w2);
                float2 g0 = __half22float2(h0), g1 = __half22float2(h1);
                float2 g2 = __half22float2(h2), g3 = __half22float2(h3);
                ax += f0 * g0.x + f1 * g1.x + f2 * g2.x + f3 * g3.x;
                ay += f0 * g0.y + f1 * g1.y + f2 * g2.y + f3 * g3.y;
            }
            for (; p < end; ++p) {
                int e0 = ent[p];
                __half2 h0 = hws2[(size_t)((e0 >> 2) & 0x1FFFF) * 16 + j2];
                float f0 = ((e0 & 3) == 0) ? w0 : (((e0 & 3) == 1) ? w1 : w2);
                float2 g0 = __half22float2(h0);
                ax += f0 * g0.x; ay += f0 * g0.y;
            }
            float2 self = __half22float2(hws2[(size_t)n * 16 + j2]);
            float di = dl[lc];
            rx = fmaxf(di * (ax + self.x) + gb[2 * j2], 0.0f);
            ry = fmaxf(di * (ay + self.y) + gb[2 * j2 + 1], 0.0f);
        }
        res[lc * 33 + 2 * j2]     = rx;
        res[lc * 33 + 2 * j2 + 1] = ry;
    }
    __syncthreads();
    // run-length pool over sorted batch: ~1-2 graphs per bucket.
    if (t < 32) {
        int j = t;
        float sum = 0.0f; int g0 = bl[0];
        for (int lc = 0; lc < 64; ++lc) {
            if (bl[lc] < 0) break;
            float val = res[lc * 33 + j];
            if (bl[lc] != g0) { atomicAdd(&pooled[g0 * 32 + j], sum); sum = 0.0f; g0 = bl[lc]; }
            sum += val;
        }
        if (g0 >= 0) atomicAdd(&pooled[g0 * 32 + j], sum);
    }
}

// k7: head: z = relu(pooled @ fc1_W + fc1_b); out = z @ out_W + out_b
__global__ void k7_head(const float* __restrict__ pooled, const float* __restrict__ fc1_W,
                        const float* __restrict__ fc1_b, const float* __restrict__ out_W,
                        const float* __restrict__ out_b, float* __restrict__ out,
                        int n_graphs) {
    __shared__ float Wl[32 * 32];
    __shared__ float bl[32];
    __shared__ float owl[32];
    int t = threadIdx.x;
    for (int idx = t; idx < 1024; idx += BLK) Wl[idx] = fc1_W[idx];
    if (t < 32) { bl[t] = fc1_b[t]; owl[t] = out_W[t]; }
    __syncthreads();
    if (t < n_graphs) {
        float p[32];
#pragma unroll
        for (int k = 0; k < 32; ++k) p[k] = pooled[t * 32 + k];
        float acc = 0.0f;
        for (int j = 0; j < 32; ++j) {
            float z = bl[j];
#pragma unroll
            for (int k = 0; k < 32; ++k) z += p[k] * Wl[k * 32 + j];
            z = fmaxf(z, 0.0f);
            acc += z * owl[j];
        }
        out[t] = acc + out_b[0];
    }
}

static inline size_t align_up(size_t v, size_t a) { return (v + a - 1) & ~(a - 1); }

extern "C" void kernel_launch(void* const* d_in, const int* in_sizes, int n_in,
                              void* d_out, int out_size, void* d_ws, size_t ws_size,
                              hipStream_t stream) {
    const float* x     = (const float*)d_in[0];
    const int*   ei    = (const int*)d_in[1];
    const int*   batch = (const int*)d_in[2];
    const int*   km    = (const int*)d_in[3];
    const int*   um    = (const int*)d_in[4];
    const int*   om    = (const int*)d_in[5];
    const float* mw    = (const float*)d_in[6];
    const float* emb_W = (const float*)d_in[7];
    const float* emb_b = (const float*)d_in[8];
    const float* gcn_W = (const float*)d_in[9];
    const float* gcn_b = (const float*)d_in[10];
    const float* fc1_W = (const float*)d_in[11];
    const float* fc1_b = (const float*)d_in[12];
    const float* out_W = (const float*)d_in[13];
    const float* out_b = (const float*)d_in[14];

    const int n_nodes  = in_sizes[0] / 64;
    const int n_edges  = in_sizes[1] / 2;
    const int s0 = in_sizes[3], s1 = in_sizes[4], s2 = in_sizes[5];
    const int n_graphs = out_size;  // 256

    const int* row = ei;
    const int* col = ei + n_edges;

    const int NB  = (n_nodes + 63) >> 6;   // 1563 buckets of 64 nodes
    const int nbs = (NB + 7) / 8;          // buckets per slice (8 slices)

    // ---- workspace layout (~28.3 MB) ----
    char* base = (char*)d_ws;
    float*   dinv   = (float*)base;   base += (size_t)n_nodes * 4;
    float*   pooled = (float*)base;   base += (size_t)n_graphs * 32 * 4;   // zeroed
    int*     cnt    = (int*)base;     base += (size_t)NCHUNK * NB * 4;     // 3.2 MB
    int*     offT   = (int*)base;     base += (size_t)NB * NCHUNK * 4;     // 3.2 MB
    int*     tot    = (int*)base;     base += (size_t)NB * 4;
    int*     base_  = (int*)base;     base += (size_t)(NB + 1) * 4;
    float*   Wfull  = (float*)base;   base += 2048 * 4;
    float*   hWbias = (float*)base;   base += 32 * 4;
    uint8_t* ewc    = (uint8_t*)base; base += align_up((size_t)n_edges, 64);
    int*     csrB   = (int*)base;     base += (size_t)n_edges * 4;         // 12 MB
    base = (char*)align_up((size_t)base, 64);
    __half*  hWs    = (__half*)base;  base += (size_t)n_nodes * 32 * 2;    // 6.4 MB

    hipMemsetAsync(pooled, 0, (size_t)n_graphs * 32 * 4, stream);

    k1_cls<<<(s0 + s1 + s2 + BLK - 1) / BLK, BLK, 0, stream>>>(km, um, om, s0, s1, s2, ewc);
    kA_count<<<NCHUNK, BLK, 0, stream>>>(col, cnt, n_edges, NB);
    kB_col<<<NB, BLK, 0, stream>>>(cnt, offT, tot, NB);
    kBase<<<1, BLK, 0, stream>>>(tot, base_, NB);
    kC_scatter<<<NCHUNK * 8, BLK, 0, stream>>>(row, col, ewc, base_, offT, csrB,
                                               n_edges, NB, nbs);
    kDeg<<<NB, BLK, 0, stream>>>(base_, csrB, mw, dinv, n_nodes);
    k3_weights<<<8, BLK, 0, stream>>>(emb_W, emb_b, gcn_W, Wfull, hWbias);
    k4_gemm<<<(n_nodes + 7) / 8, BLK, 0, stream>>>(x, Wfull, hWbias, dinv, hWs, n_nodes);
    kD_gather<<<NB, BLK, 0, stream>>>(base_, csrB, (const __half2*)hWs, dinv, mw,
                                      gcn_b, batch, pooled, n_nodes);
    k7_head<<<1, BLK, 0, stream>>>(pooled, fc1_W, fc1_b, out_W, out_b, (float*)d_out, n_graphs);
}